// Round 14
// baseline (36.247 us; speedup 1.0000x reference)
//
#include <hip/hip_runtime.h>

#define RADIUS 5
#define WIN    11
#define WIN2   121
#define KCLS   6
#define HH     128
#define WW     128
#define BB     4
#define NPIX   (HH*WW)
#define TPB    256                  // 4 lanes per pixel, 64 px (half row)
#define NBLK   (BB*HH*2)            // 1024 blocks
#define PXB    64                   // pixels per block

__global__ __launch_bounds__(TPB, 4) void ncut_main(
    const float* __restrict__ labels,
    const float* __restrict__ weights,
    float* __restrict__ part) {
  __shared__ float shred[4 * 12];

  const int tid = threadIdx.x;
  const int blk = blockIdx.x;
  const int b   = blk >> 8;                 // 256 blocks per image
  const int rem = blk & 255;
  const int y0  = rem >> 1;
  const int x0  = (rem & 1) * PXB;

  // ---- per-thread: pixel px, quad set {4g+q} on the ALIGNED quad grid ----
  const int px = tid >> 2;          // 0..63
  const int q  = tid & 3;           // 0..3
  const size_t pxg = (size_t)b * NPIX + (size_t)y0 * WW + x0 + px;
  const int S  = (int)(pxg & 3);    // row-start misalignment (floats)
  const float* wal = weights + pxg * WIN2 - S;   // 16B-aligned base
  const int d  = 4 * q - S;         // tap offset of this lane's quads

  // label plane base (class k at +k*NPIX)
  const float* lab0 = labels + (size_t)b * KCLS * NPIX;
  const int gx0 = x0 + px - RADIUS; // gx = gx0 + ox

  float a0 = 0.f, a1 = 0.f, a2 = 0.f, a3 = 0.f, a4 = 0.f, a5 = 0.f;
  float wsum = 0.f;

#pragma unroll
  for (int g = 0; g < 8; ++g) {
    // q==3,g==7 would be quad 31 (OOB, taps all >120): clamp to quad 30
    const int kq = (g == 7) ? ((q == 3) ? 30 : 28 + q) : 4 * g + q;
    const float4 wv = *reinterpret_cast<const float4*>(wal + 4 * kq);
#pragma unroll
    for (int m = 0; m < 4; ++m) {
      const float w = (m == 0) ? wv.x : (m == 1) ? wv.y : (m == 2) ? wv.z : wv.w;
      const int t  = 16 * g + m + d;     // tap index (edges: <0 or >120)
      bool vwin = true;
      if (g == 0) vwin = (q != 0) | (m >= S);              // t >= 0
      if (g == 7) vwin = (q < 2) | ((q == 2) & (m <= S));  // t <= 120
      const float w0 = vwin ? w : 0.0f;  // window-masked weight
      const int tc  = vwin ? t : 0;
      const int r   = (tc * 5958) >> 16;       // tc/11, exact for 0<=tc<=123
      const int gy  = y0 - RADIUS + r;
      const int gx  = gx0 + (tc - 11 * r);
      const bool vi = ((unsigned)gy < (unsigned)HH) & ((unsigned)gx < (unsigned)WW);
      const int off = vi ? (gy * WW + gx) : 0;   // clamped, always safe
      const float ww = vi ? w0 : 0.0f;           // zero-pad contribution
      wsum += w0;                                // den counts all window taps
      a0 += ww * lab0[off];
      a1 += ww * lab0[1 * NPIX + off];
      a2 += ww * lab0[2 * NPIX + off];
      a3 += ww * lab0[3 * NPIX + off];
      a4 += ww * lab0[4 * NPIX + off];
      a5 += ww * lab0[5 * NPIX + off];
    }
  }

  // ---- reduce the 4 q-lanes (xor 1,2) ----
#pragma unroll
  for (int off = 1; off <= 2; off <<= 1) {
    wsum += __shfl_xor(wsum, off);
    a0 += __shfl_xor(a0, off); a1 += __shfl_xor(a1, off);
    a2 += __shfl_xor(a2, off); a3 += __shfl_xor(a3, off);
    a4 += __shfl_xor(a4, off); a5 += __shfl_xor(a5, off);
  }

  // ---- num/den per pixel: center label value (always in-image, L1-hot) ----
  const int coff = y0 * WW + x0 + px;
  float nv[KCLS], dv[KCLS];
  const float wpv[KCLS] = {a0, a1, a2, a3, a4, a5};
#pragma unroll
  for (int k = 0; k < KCLS; ++k) {
    const float p = lab0[k * NPIX + coff];
    nv[k] = p * wpv[k];
    dv[k] = p * wsum;
  }

  // ---- reduce across the 16 pixels of this wave (lane bits 2..5) ----
#pragma unroll
  for (int off = 4; off <= 32; off <<= 1) {
#pragma unroll
    for (int k = 0; k < KCLS; ++k) {
      nv[k] += __shfl_xor(nv[k], off);
      dv[k] += __shfl_xor(dv[k], off);
    }
  }
  const int wave = tid >> 6;
  if ((tid & 63) == 0) {
#pragma unroll
    for (int k = 0; k < KCLS; ++k) {
      shred[wave * 12 + k]     = nv[k];
      shred[wave * 12 + 6 + k] = dv[k];
    }
  }
  __syncthreads();
  if (tid < 12) {
    float s = 0.f;
#pragma unroll
    for (int w = 0; w < 4; ++w) s += shred[w * 12 + tid];
    part[blk * 12 + tid] = s;
  }
}

// ---- final: L = num/den per (b,k); out = K - (1/B) * sum |L| ----
// 8 segments x 32 (b,k)-slots, 32 block-partials each, LDS reduce.
__global__ __launch_bounds__(256) void ncut_final(
    const float* __restrict__ part, float* __restrict__ out) {
  __shared__ float shf[8 * 48];
  const int t   = threadIdx.x;
  const int seg = t >> 5;           // 0..7
  const int bk  = t & 31;           // active < 24
  if (bk < 24) {
    const int b = bk / KCLS;
    const int k = bk - b * KCLS;
    const int r0 = b * 256 + seg * 32;
    float num = 0.f, den = 0.f;
#pragma unroll 4
    for (int i = 0; i < 32; ++i) {
      const float* p = part + (size_t)(r0 + i) * 12;
      num += p[k];
      den += p[6 + k];
    }
    shf[seg * 48 + bk * 2]     = num;
    shf[seg * 48 + bk * 2 + 1] = den;
  }
  __syncthreads();
  float val = 0.f;
  if (t < 24) {
    float n = 0.f, d = 0.f;
#pragma unroll
    for (int s = 0; s < 8; ++s) {
      n += shf[s * 48 + t * 2];
      d += shf[s * 48 + t * 2 + 1];
    }
    val = fabsf(n / d) * (1.0f / BB);
  }
  if (t < 64) {
#pragma unroll
    for (int off = 16; off; off >>= 1) val += __shfl_down(val, off);
    if (t == 0) out[0] = (float)KCLS - val;
  }
}

extern "C" void kernel_launch(void* const* d_in, const int* in_sizes, int n_in,
                              void* d_out, int out_size, void* d_ws, size_t ws_size,
                              hipStream_t stream) {
  const float* labels  = (const float*)d_in[0];
  const float* weights = (const float*)d_in[1];
  float* out  = (float*)d_out;
  float* part = (float*)d_ws;      // 1024 blocks * 12 floats = 49152 B

  ncut_main<<<NBLK, TPB, 0, stream>>>(labels, weights, part);
  ncut_final<<<1, 256, 0, stream>>>(part, out);
}

// Round 15
// 19.002 us; speedup vs baseline: 1.9075x; 1.9075x over previous
//
#include <hip/hip_runtime.h>

#define RADIUS 5
#define WIN    11
#define WIN2   121
#define KCLS   6
#define HH     128
#define WW     128
#define BB     4
#define NPIX   (HH*WW)
#define TPB    128                  // 4 lanes per pixel, 32 px per block
#define PXB    32                   // pixels per block
#define NBLK   (BB*HH*(WW/PXB))     // 2048 blocks
#define LABW   (PXB + 2*RADIUS)     // 42 cols
#define NSITE  (WIN*LABW)           // 462 sites
#define PLSTR  (NSITE*2)            // floats per class-pair plane

__global__ __launch_bounds__(TPB, 4) void ncut_main(
    const float* __restrict__ labels,
    const float* __restrict__ weights,
    float* __restrict__ part) {
  // label tile: 3 pair-planes of [site][2 classes] -> ds_read_b64 per pair
  __shared__ float shl[3 * PLSTR];    // 2772 floats = 11.1 KB
  __shared__ float shred[2 * 12];

  const int tid = threadIdx.x;
  const int blk = blockIdx.x;
  const int b   = blk >> 9;                 // 512 blocks per image
  const int rem = blk & 511;
  const int y0  = rem >> 2;
  const int x0  = (rem & 3) * PXB;

  // ---- stage zero-padded label tile, class-pair interleaved ----
  const float* labB = labels + (size_t)b * KCLS * NPIX;
  for (int s = tid; s < NSITE; s += TPB) {
    const int tr = s / LABW;
    const int tc = s - tr * LABW;
    const int gy = y0 - RADIUS + tr;
    const int gx = x0 + tc - RADIUS;
    const bool ok = ((unsigned)gy < (unsigned)HH) & ((unsigned)gx < (unsigned)WW);
    const float* lp = labB + (size_t)gy * WW + gx;
#pragma unroll
    for (int p = 0; p < 3; ++p) {
      float2 v = make_float2(0.f, 0.f);
      if (ok) {
        v.x = lp[(size_t)(2 * p) * NPIX];
        v.y = lp[(size_t)(2 * p + 1) * NPIX];
      }
      *reinterpret_cast<float2*>(shl + p * PLSTR + 2 * s) = v;
    }
  }
  __syncthreads();

  // ---- per-thread: pixel px, quad set {4g+q} on the ALIGNED quad grid ----
  const int px = tid >> 2;          // 0..31
  const int q  = tid & 3;           // 0..3
  const size_t pxg = (size_t)b * NPIX + (size_t)y0 * WW + x0 + px;
  const int S  = (int)(pxg & 3);    // row-start misalignment (floats)
  const float* wal = weights + pxg * WIN2 - S;   // 16B-aligned base
  const int T0 = 4 * q - S;         // tap offset of this lane's quads

  float2 a0 = make_float2(0.f, 0.f);
  float2 a1 = make_float2(0.f, 0.f);
  float2 a2 = make_float2(0.f, 0.f);
  float wsum = 0.f;

#pragma unroll
  for (int g = 0; g < 8; ++g) {
    // q==3,g==7 would be quad 31 (OOB, taps all >120): clamp to quad 30
    const int kq = (g == 7) ? ((q == 3) ? 30 : 28 + q) : 4 * g + q;
    const float4 wv = *reinterpret_cast<const float4*>(wal + 4 * kq);
#pragma unroll
    for (int m = 0; m < 4; ++m) {
      float w = (m == 0) ? wv.x : (m == 1) ? wv.y : (m == 2) ? wv.z : wv.w;
      int   t = 16 * g + m + T0;    // tap index (edges: <0 or >120)
      bool valid = true;
      if (g == 0) valid = (q != 0) | (m >= S);             // t >= 0
      if (g == 7) valid = (q < 2) | ((q == 2) & (m <= S)); // t <= 120
      if (!valid) { w = 0.0f; t = 0; }
      const int r  = (t * 5958) >> 16;    // t/11, exact for 0<=t<=123
      const int li = px + t + (LABW - WIN) * r;   // px + row*42 + col
      const float2 v0 = *reinterpret_cast<const float2*>(shl + 2 * li);
      const float2 v1 = *reinterpret_cast<const float2*>(shl + PLSTR + 2 * li);
      const float2 v2 = *reinterpret_cast<const float2*>(shl + 2 * PLSTR + 2 * li);
      wsum += w;
      a0.x += w * v0.x; a0.y += w * v0.y;
      a1.x += w * v1.x; a1.y += w * v1.y;
      a2.x += w * v2.x; a2.y += w * v2.y;
    }
  }

  // ---- reduce the 4 q-lanes (xor 1,2) ----
#pragma unroll
  for (int off = 1; off <= 2; off <<= 1) {
    wsum += __shfl_xor(wsum, off);
    a0.x += __shfl_xor(a0.x, off); a0.y += __shfl_xor(a0.y, off);
    a1.x += __shfl_xor(a1.x, off); a1.y += __shfl_xor(a1.y, off);
    a2.x += __shfl_xor(a2.x, off); a2.y += __shfl_xor(a2.y, off);
  }

  // ---- num/den per pixel (center site = 5*42 + 5) ----
  const int lc = px + 5 * LABW + 5;
  const float2 c0 = *reinterpret_cast<const float2*>(shl + 2 * lc);
  const float2 c1 = *reinterpret_cast<const float2*>(shl + PLSTR + 2 * lc);
  const float2 c2 = *reinterpret_cast<const float2*>(shl + 2 * PLSTR + 2 * lc);
  float nv[KCLS] = {c0.x * a0.x, c0.y * a0.y, c1.x * a1.x,
                    c1.y * a1.y, c2.x * a2.x, c2.y * a2.y};
  float dv[KCLS] = {c0.x * wsum, c0.y * wsum, c1.x * wsum,
                    c1.y * wsum, c2.x * wsum, c2.y * wsum};

  // ---- reduce across the 16 pixels of this wave (lane bits 2..5) ----
#pragma unroll
  for (int off = 4; off <= 32; off <<= 1) {
#pragma unroll
    for (int k = 0; k < KCLS; ++k) {
      nv[k] += __shfl_xor(nv[k], off);
      dv[k] += __shfl_xor(dv[k], off);
    }
  }
  const int wave = tid >> 6;
  if ((tid & 63) == 0) {
#pragma unroll
    for (int k = 0; k < KCLS; ++k) {
      shred[wave * 12 + k]     = nv[k];
      shred[wave * 12 + 6 + k] = dv[k];
    }
  }
  __syncthreads();
  // transposed partials: part[slot][NBLK] -> final kernel reads coalesced
  if (tid < 12) {
    part[tid * NBLK + blk] = shred[tid] + shred[12 + tid];
  }
}

// ---- final: L = num/den per (b,k); out = K - (1/B) * sum |L| ----
// 48 sums (isden,b,k) x 4 segments of 128 consecutive floats, coalesced f4.
__global__ __launch_bounds__(256) void ncut_final(
    const float* __restrict__ part, float* __restrict__ out) {
  __shared__ float shf[4 * 48];
  const int t     = threadIdx.x;
  const int sumid = t >> 2;         // 0..63, active < 48
  const int seg   = t & 3;
  if (sumid < 48) {
    const int isden = sumid / 24;
    const int bk    = sumid - isden * 24;
    const int b     = bk / KCLS;
    const int k     = bk - b * KCLS;
    const int slot  = isden * KCLS + k;
    const float* p  = part + (size_t)slot * NBLK + b * (NBLK / BB) + seg * 128;
    float s = 0.f;
#pragma unroll 8
    for (int i = 0; i < 32; ++i) {
      const float4 v = *reinterpret_cast<const float4*>(p + 4 * i);
      s += v.x + v.y + v.z + v.w;
    }
    shf[seg * 48 + sumid] = s;
  }
  __syncthreads();
  float val = 0.f;
  if (t < 24) {
    float num = 0.f, den = 0.f;
#pragma unroll
    for (int sg = 0; sg < 4; ++sg) {
      num += shf[sg * 48 + t];
      den += shf[sg * 48 + 24 + t];
    }
    val = fabsf(num / den) * (1.0f / BB);
  }
  if (t < 64) {
#pragma unroll
    for (int off = 32; off; off >>= 1) val += __shfl_down(val, off);
    if (t == 0) out[0] = (float)KCLS - val;
  }
}

extern "C" void kernel_launch(void* const* d_in, const int* in_sizes, int n_in,
                              void* d_out, int out_size, void* d_ws, size_t ws_size,
                              hipStream_t stream) {
  const float* labels  = (const float*)d_in[0];
  const float* weights = (const float*)d_in[1];
  float* out  = (float*)d_out;
  float* part = (float*)d_ws;      // 12 * 2048 floats = 98304 B

  ncut_main<<<NBLK, TPB, 0, stream>>>(labels, weights, part);
  ncut_final<<<1, 256, 0, stream>>>(part, out);
}